// Round 9
// baseline (317.585 us; speedup 1.0000x reference)
//
#include <hip/hip_runtime.h>
#include <math.h>

constexpr int BB = 2, NN = 4096, MM = 16384;
constexpr int JT = 32, IT = 8;           // grid: 32 col-blocks x 8 row-blocks x 2
constexpr int RT = NN / IT;              // 512 rows per block
constexpr int CW = MM / JT;              // 512 cols per block

// No global atomics anywhere (R1-R8 were atomic-writeback-bound at ~400 GB/s:
// dur ≈ WRITE_SIZE/400GB/s every round). Each block writes its partial mins to
// a distinct slot with plain stores; reduce kernels combine. Deterministic.

// block 256 = 16 tx (cols) x 16 ty (rows). Per col-chunk cc (4 x 128 cols):
// 8 cols/thread in regs FROM GLOBAL (compiler never re-reads global in-loop,
// unlike LDS - the R4-R8 lesson). Rows broadcast from transposed LDS.
__global__ __launch_bounds__(256, 2) void pair_kernel(
    const float* __restrict__ sampled,   // [BB][NN][4]
    const float* __restrict__ raw,       // [BB][MM][4]
    float* __restrict__ rowpart,         // [JT][BB][NN]
    float* __restrict__ colpart)         // [IT][BB][MM]
{
    __shared__ float4 sT[RT];            // row i -> slot (i&15)*32 + (i>>4)
    __shared__ float cred[4][128];

    const int b  = blockIdx.z;
    const int i0 = blockIdx.y * RT;
    const int j0 = blockIdx.x * CW;
    const int tid = threadIdx.x;
    const int tx = tid & 15, ty = tid >> 4;
    const int wv = tid >> 6, lane = tid & 63;

    const float4* sb = (const float4*)sampled + (size_t)b * NN + i0;
    const float4* rb = (const float4*)raw     + (size_t)b * MM + j0;

    // stage 512 rows (2/thread), |s|^2 folded into .w, transposed slots
    for (int k = tid; k < RT; k += 256) {
        float4 v = sb[k];
        v.w = fmaf(v.z, v.z, fmaf(v.y, v.y, v.x * v.x));
        sT[(k & 15) * 32 + (k >> 4)] = v;
    }
    __syncthreads();

    const float INF = __uint_as_float(0x7F800000u);
    float rmin[2][16];                   // fully static-indexed (all loops unrolled)
#pragma unroll
    for (int rc = 0; rc < 2; ++rc)
#pragma unroll
        for (int q = 0; q < 16; ++q) rmin[rc][q] = INF;

    float* cpb = colpart + ((size_t)blockIdx.y * BB + b) * MM + j0;

#pragma unroll
    for (int cc = 0; cc < 4; ++cc) {
        // this thread's 8 cols from global (L1/L2-hot after first touch)
        float rx[8], ry[8], rz[8], rn[8];
#pragma unroll
        for (int r = 0; r < 8; ++r) {
            float4 v = rb[cc * 128 + tx * 8 + r];
            rn[r] = fmaf(v.z, v.z, fmaf(v.y, v.y, v.x * v.x));
            rx[r] = -2.f * v.x; ry[r] = -2.f * v.y; rz[r] = -2.f * v.z;
        }
        float cmin[8] = {INF, INF, INF, INF, INF, INF, INF, INF};

#pragma unroll
        for (int rc = 0; rc < 2; ++rc) {
#pragma unroll
            for (int q = 0; q < 16; ++q) {
                float4 sv = sT[q * 32 + rc * 16 + ty];  // 4 distinct slots/wave: conflict-free
                float best = INF;
#pragma unroll
                for (int r = 0; r < 8; ++r) {
                    float t = sv.w + rn[r];
                    t = fmaf(sv.x, rx[r], t);
                    t = fmaf(sv.y, ry[r], t);
                    t = fmaf(sv.z, rz[r], t);
                    cmin[r] = fminf(cmin[r], t);
                    best    = fminf(best, t);
                }
                rmin[rc][q] = fminf(rmin[rc][q], best);
            }
        }
        // col-min: cross-ty in-wave (masks 16,32), then cross-wave via LDS, store
#pragma unroll
        for (int m = 16; m < 64; m <<= 1)
#pragma unroll
            for (int r = 0; r < 8; ++r)
                cmin[r] = fminf(cmin[r], __shfl_xor(cmin[r], m, 64));
        if (lane < 16) {
#pragma unroll
            for (int r = 0; r < 8; ++r) cred[wv][lane * 8 + r] = cmin[r];
        }
        __syncthreads();
        if (tid < 128) {
            float v = fminf(fminf(cred[0][tid], cred[1][tid]),
                            fminf(cred[2][tid], cred[3][tid]));
            cpb[cc * 128 + tid] = fmaxf(v, 0.f);
        }
        __syncthreads();
    }

    // row-min: cross-tx reduce, one plain store per row (tx==0 lanes)
    float* rpb = rowpart + ((size_t)blockIdx.x * BB + b) * NN + i0;
#pragma unroll
    for (int rc = 0; rc < 2; ++rc) {
#pragma unroll
        for (int q = 0; q < 16; ++q) {
            float m = rmin[rc][q];
            m = fminf(m, __shfl_xor(m, 1, 64));
            m = fminf(m, __shfl_xor(m, 2, 64));
            m = fminf(m, __shfl_xor(m, 4, 64));
            m = fminf(m, __shfl_xor(m, 8, 64));
            if (tx == 0)
                rpb[rc * 256 + ty * 16 + q] = fmaxf(m, 0.f);
        }
    }
}

// 64 blocks: b = k>>5, slice s = k&31. Min over partials, then sqrt-sums.
__global__ __launch_bounds__(256) void reduce1_kernel(
    const float* __restrict__ rowpart,
    const float* __restrict__ colpart,
    float* __restrict__ part)            // [64][3]
{
    const int k = blockIdx.x, b = k >> 5, s = k & 31;
    const int tid = threadIdx.x;
    const float INF = __uint_as_float(0x7F800000u);

    float sB = 0.f;
#pragma unroll
    for (int h = 0; h < 2; ++h) {
        const int col = s * 512 + h * 256 + tid;
        float v = INF;
        for (int it = 0; it < IT; ++it)
            v = fminf(v, colpart[((size_t)it * BB + b) * MM + col]);
        sB += sqrtf(v);
    }

    float sF = 0.f, mF = 0.f;
    if (tid < 128) {
        const int row = s * 128 + tid;
        float v = INF;
        for (int jt = 0; jt < JT; ++jt)
            v = fminf(v, rowpart[((size_t)jt * BB + b) * NN + row]);
        float d = sqrtf(v);
        sF = d; mF = d;
    }

    for (int m = 1; m < 64; m <<= 1) {
        sB += __shfl_xor(sB, m, 64);
        sF += __shfl_xor(sF, m, 64);
        mF = fmaxf(mF, __shfl_xor(mF, m, 64));
    }
    __shared__ float red[3][4];
    const int lane = tid & 63, w = tid >> 6;
    if (lane == 0) { red[0][w] = sB; red[1][w] = sF; red[2][w] = mF; }
    __syncthreads();
    if (tid == 0) {
        sB = red[0][0] + red[0][1] + red[0][2] + red[0][3];
        sF = red[1][0] + red[1][1] + red[1][2] + red[1][3];
        mF = fmaxf(fmaxf(red[2][0], red[2][1]), fmaxf(red[2][2], red[2][3]));
        part[k * 3 + 0] = sB; part[k * 3 + 1] = sF; part[k * 3 + 2] = mF;
    }
}

__global__ void reduce2_kernel(const float* __restrict__ part,
                               float* __restrict__ out)
{
    const int lane = threadIdx.x;   // 64 threads; lanes 0..31 = b0, 32..63 = b1
    float sB = part[lane * 3 + 0];
    float sF = part[lane * 3 + 1];
    float mF = part[lane * 3 + 2];
    for (int m = 1; m < 32; m <<= 1) {
        sB += __shfl_xor(sB, m, 64);
        sF += __shfl_xor(sF, m, 64);
        mF = fmaxf(mF, __shfl_xor(mF, m, 64));
    }
    float oB = __shfl_xor(sB, 32, 64);
    float oF = __shfl_xor(sF, 32, 64);
    float oM = __shfl_xor(mF, 32, 64);
    if (lane == 0) {
        float l0 = 5.f * sB / (float)MM + sF / (float)NN + mF;
        float l1 = 5.f * oB / (float)MM + oF / (float)NN + oM;
        *out = 0.5f * (l0 + l1);
    }
}

extern "C" void kernel_launch(void* const* d_in, const int* in_sizes, int n_in,
                              void* d_out, int out_size, void* d_ws, size_t ws_size,
                              hipStream_t stream) {
    const float* sampled = (const float*)d_in[0];
    const float* raw     = (const float*)d_in[1];
    float* rowpart = (float*)d_ws;                          // JT*BB*NN   = 256K floats
    float* colpart = rowpart + (size_t)JT * BB * NN;        // IT*BB*MM   = 256K floats
    float* part    = colpart + (size_t)IT * BB * MM;        // 192 floats
    float* out     = (float*)d_out;

    pair_kernel<<<dim3(JT, IT, BB), 256, 0, stream>>>(sampled, raw, rowpart, colpart);
    reduce1_kernel<<<64, 256, 0, stream>>>(rowpart, colpart, part);
    reduce2_kernel<<<1, 64, 0, stream>>>(part, out);
}

// Round 10
// 52.156 us; speedup vs baseline: 6.0891x; 6.0891x over previous
//
#include <hip/hip_runtime.h>
#include <math.h>

constexpr int BB = 2, NN = 4096, MM = 16384;
constexpr int PTS = 4;                   // owned points per lane (16 regs - proven safe)
constexpr int ISA = 16;                  // i-slices, colmin pass
constexpr int JSB = 64;                  // j-slices, rowmin pass
constexpr int JBA = MM / (256 * PTS);    // 16 j-blocks (role A)
constexpr int IBB = NN / (256 * PTS);    // 4  i-blocks (role B)
constexpr int GA  = JBA * ISA * BB;      // 512 role-A blocks
constexpr int GB  = IBB * JSB * BB;      // 512 role-B blocks

// The only primitives that never failed in R1-R9:
//  - owned points: ONE global float4 load per point, <=16 floats/lane resident
//  - scanned points: wave-UNIFORM address -> s_load_dwordx4 (scalar pipe; no
//    LDS unit, no VMEM, no shuffles, nothing for the allocator to re-read)
//  - per-lane scalar accumulators; plain partial stores (no atomics: R1-R8
//    were atomic-writeback-bound at ~400 GB/s)
__device__ __forceinline__ void scan_pass(
    const float4* __restrict__ own,      // owned-point base (thread-indexed)
    const float4* __restrict__ scan,     // scanned-point base (uniform-indexed)
    float* __restrict__ outpart,         // partial-min out (thread-indexed)
    int tid, int scan0, int scanN)
{
    const float INF = __uint_as_float(0x7F800000u);
    float px[PTS], py[PTS], pz[PTS], pn[PTS], acc[PTS];
#pragma unroll
    for (int p = 0; p < PTS; ++p) {
        float4 v = own[p * 256 + tid];   // coalesced: lane-consecutive float4
        pn[p] = fmaf(v.z, v.z, fmaf(v.y, v.y, v.x * v.x));
        px[p] = -2.f * v.x; py[p] = -2.f * v.y; pz[p] = -2.f * v.z;
        acc[p] = INF;
    }
#pragma unroll 4
    for (int k = 0; k < scanN; ++k) {
        float4 sv = scan[scan0 + k];     // uniform -> s_load_dwordx4
        float nrm = fmaf(sv.z, sv.z, fmaf(sv.y, sv.y, sv.x * sv.x));
#pragma unroll
        for (int p = 0; p < PTS; ++p) {
            float t = nrm + pn[p];
            t = fmaf(sv.x, px[p], t);
            t = fmaf(sv.y, py[p], t);
            t = fmaf(sv.z, pz[p], t);
            acc[p] = fminf(acc[p], t);
        }
    }
#pragma unroll
    for (int p = 0; p < PTS; ++p)
        outpart[p * 256 + tid] = fmaxf(acc[p], 0.f);
}

// one launch, two roles: blocks [0,GA) = colmin pass, [GA,GA+GB) = rowmin pass
__global__ __launch_bounds__(256) void pair_kernel(
    const float* __restrict__ sampled,   // [BB][NN][4]
    const float* __restrict__ raw,       // [BB][MM][4]
    float* __restrict__ rowpart,         // [JSB][BB][NN]
    float* __restrict__ colpart)         // [ISA][BB][MM]
{
    const int g = blockIdx.x, tid = threadIdx.x;
    if (g < GA) {
        const int jb = g % JBA, is = (g / JBA) % ISA, b = g / (JBA * ISA);
        const float4* own  = (const float4*)raw     + (size_t)b * MM + jb * 1024;
        const float4* scan = (const float4*)sampled + (size_t)b * NN;
        float* outp = colpart + ((size_t)is * BB + b) * MM + jb * 1024;
        scan_pass(own, scan, outp, tid, is * (NN / ISA), NN / ISA);   // 256 iters
    } else {
        const int h = g - GA;
        const int ib = h % IBB, js = (h / IBB) % JSB, b = h / (IBB * JSB);
        const float4* own  = (const float4*)sampled + (size_t)b * NN + ib * 1024;
        const float4* scan = (const float4*)raw     + (size_t)b * MM;
        float* outp = rowpart + ((size_t)js * BB + b) * NN + ib * 1024;
        scan_pass(own, scan, outp, tid, js * (MM / JSB), MM / JSB);   // 256 iters
    }
}

// 128 blocks: b = k>>6, slice s = k&63. Min over partials, sqrt, partial sums.
__global__ __launch_bounds__(256) void reduce1_kernel(
    const float* __restrict__ rowpart,
    const float* __restrict__ colpart,
    float* __restrict__ part)            // [128][3]
{
    const int k = blockIdx.x, b = k >> 6, s = k & 63;
    const int tid = threadIdx.x;
    const float INF = __uint_as_float(0x7F800000u);

    // cols: 256 per slice, min over ISA partials (coalesced strided reads)
    const int col = s * 256 + tid;
    float v = INF;
#pragma unroll 4
    for (int is = 0; is < ISA; ++is)
        v = fminf(v, colpart[((size_t)is * BB + b) * MM + col]);
    float sB = sqrtf(v);

    // rows: 64 per slice; each wave-quarter jq covers JSB/4 partials
    const int row = s * 64 + (tid & 63);
    const int jq  = tid >> 6;
    float w = INF;
#pragma unroll 4
    for (int q = 0; q < JSB / 4; ++q)
        w = fminf(w, rowpart[(((size_t)jq * (JSB / 4) + q) * BB + b) * NN + row]);
    __shared__ float rred[4][64];
    rred[jq][tid & 63] = w;
    __syncthreads();
    float sF = 0.f, mF = 0.f;
    if (tid < 64) {
        float rmn = fminf(fminf(rred[0][tid], rred[1][tid]),
                          fminf(rred[2][tid], rred[3][tid]));
        float d = sqrtf(rmn);
        sF = d; mF = d;
    }

    for (int m = 1; m < 64; m <<= 1) {
        sB += __shfl_xor(sB, m, 64);
        sF += __shfl_xor(sF, m, 64);
        mF = fmaxf(mF, __shfl_xor(mF, m, 64));
    }
    __shared__ float red[3][4];
    const int lane = tid & 63, wv = tid >> 6;
    if (lane == 0) { red[0][wv] = sB; red[1][wv] = sF; red[2][wv] = mF; }
    __syncthreads();
    if (tid == 0) {
        part[k * 3 + 0] = red[0][0] + red[0][1] + red[0][2] + red[0][3];
        part[k * 3 + 1] = red[1][0] + red[1][1] + red[1][2] + red[1][3];
        part[k * 3 + 2] = fmaxf(fmaxf(red[2][0], red[2][1]),
                                fmaxf(red[2][2], red[2][3]));
    }
}

__global__ void reduce2_kernel(const float* __restrict__ part,
                               float* __restrict__ out)
{
    const int tid = threadIdx.x;         // 128 threads: wave0 = b0, wave1 = b1
    float sB = part[tid * 3 + 0];
    float sF = part[tid * 3 + 1];
    float mF = part[tid * 3 + 2];
    for (int m = 1; m < 64; m <<= 1) {
        sB += __shfl_xor(sB, m, 64);
        sF += __shfl_xor(sF, m, 64);
        mF = fmaxf(mF, __shfl_xor(mF, m, 64));
    }
    __shared__ float red[2][3];
    if ((tid & 63) == 0) { red[tid >> 6][0] = sB; red[tid >> 6][1] = sF; red[tid >> 6][2] = mF; }
    __syncthreads();
    if (tid == 0) {
        float l0 = 5.f * red[0][0] / (float)MM + red[0][1] / (float)NN + red[0][2];
        float l1 = 5.f * red[1][0] / (float)MM + red[1][1] / (float)NN + red[1][2];
        *out = 0.5f * (l0 + l1);
    }
}

extern "C" void kernel_launch(void* const* d_in, const int* in_sizes, int n_in,
                              void* d_out, int out_size, void* d_ws, size_t ws_size,
                              hipStream_t stream) {
    const float* sampled = (const float*)d_in[0];
    const float* raw     = (const float*)d_in[1];
    float* rowpart = (float*)d_ws;                          // JSB*BB*NN = 512K floats (2 MB)
    float* colpart = rowpart + (size_t)JSB * BB * NN;       // ISA*BB*MM = 512K floats (2 MB)
    float* part    = colpart + (size_t)ISA * BB * MM;       // 384 floats
    float* out     = (float*)d_out;

    pair_kernel<<<GA + GB, 256, 0, stream>>>(sampled, raw, rowpart, colpart);
    reduce1_kernel<<<128, 256, 0, stream>>>(rowpart, colpart, part);
    reduce2_kernel<<<1, 128, 0, stream>>>(part, out);
}

// Round 11
// 48.699 us; speedup vs baseline: 6.5214x; 1.0710x over previous
//
#include <hip/hip_runtime.h>
#include <math.h>

constexpr int BB = 2, NN = 4096, MM = 16384;
constexpr int JS = 16;                   // j-strips (1024 cols each)
constexpr int IG = 32;                   // i-groups (128 rows each)
constexpr unsigned INFBITS = 0x7F800000u;

typedef __attribute__((ext_vector_type(8))) short short8;
typedef __attribute__((ext_vector_type(8))) ushort ushort8;
typedef __attribute__((ext_vector_type(4))) float f32x4;

// ---------- prep: pack points into MFMA K-vectors (hi/lo split bf16) ----------
// sq[i][j] = |s|^2 + |r|^2 - 2 s.r, all folded into ONE mfma_16x16x32 K-vector:
//  k0-2 : A=hi(-2s)  B=hi(r)      k9 : A=hi(|s|^2) B=1     k11: A=1 B=hi(|r|^2)
//  k3-5 : A=hi(-2s)  B=lo(r)      k10: A=lo(|s|^2) B=1     k12: A=1 B=lo(|r|^2)
//  k6-8 : A=lo(-2s)  B=hi(r)      k13-15: 0
// Missing lo*lo term ~1e-5 relative. Fragment-linear layout: tile t, lane l
// reads 16 B at pack[t*1024 + l*16]; lanes 32-63 (k>=16) stored as zeros.
__device__ __forceinline__ ushort f2bf(float f) {
    unsigned u = __float_as_uint(f);
    u += 0x7FFF + ((u >> 16) & 1);
    return (ushort)(u >> 16);
}
__device__ __forceinline__ void split2(float v, ushort& h, ushort& l) {
    h = f2bf(v);
    l = f2bf(v - __uint_as_float(((unsigned)h) << 16));
}

__global__ __launch_bounds__(256) void pack_kernel(
    const float* __restrict__ sampled, const float* __restrict__ raw,
    ushort* __restrict__ Apack, ushort* __restrict__ Bpack)
{
    const int g = blockIdx.x * 256 + threadIdx.x;   // 0 .. 40959
    constexpr ushort ONE = 0x3F80;
    ushort8 w0, w1;
    ushort* dst;
    if (g < BB * NN) {
        float4 v = ((const float4*)sampled)[g];
        float n = fmaf(v.z, v.z, fmaf(v.y, v.y, v.x * v.x));
        ushort hx,lx,hy,ly,hz,lz,hn,ln;
        split2(-2.f * v.x, hx, lx); split2(-2.f * v.y, hy, ly);
        split2(-2.f * v.z, hz, lz); split2(n, hn, ln);
        w0 = ushort8{hx,hy,hz,hx,hy,hz,lx,ly};
        w1 = ushort8{lz,hn,ln,ONE,ONE,0,0,0};
        dst = Apack + ((size_t)(g >> 4) << 9) + ((g & 15) << 3);
    } else {
        const int p = g - BB * NN;
        float4 v = ((const float4*)raw)[p];
        float n = fmaf(v.z, v.z, fmaf(v.y, v.y, v.x * v.x));
        ushort hx,lx,hy,ly,hz,lz,hn,ln;
        split2(v.x, hx, lx); split2(v.y, hy, ly);
        split2(v.z, hz, lz); split2(n, hn, ln);
        w0 = ushort8{hx,hy,hz,lx,ly,lz,hx,hy};
        w1 = ushort8{hz,ONE,ONE,hn,ln,0,0,0};
        dst = Bpack + ((size_t)(p >> 4) << 9) + ((p & 15) << 3);
    }
    ushort8 zz = ushort8{0,0,0,0,0,0,0,0};
    *(ushort8*)(dst)       = w0;   // lanes 0-15 half (k 0-7)
    *(ushort8*)(dst + 128) = w1;   // lanes 16-31 half (k 8-15)
    *(ushort8*)(dst + 256) = zz;   // lanes 32-47 (k 16-23) = 0
    *(ushort8*)(dst + 384) = zz;   // lanes 48-63 (k 24-31) = 0
}

// ---------- pair: MFMA distance tiles + register/LDS mins ----------
// grid (JS, IG, BB); 256 thr = 4 waves. Wave w: A-tiles at rows ig*128+w*16
// and +64 (2 frags, 8 VGPR); streams the strip's 64 B-tiles from global.
// C layout (m89-verified): col=lane&15, row=(lane>>4)*4+reg.
__global__ __launch_bounds__(256, 4) void pair_kernel(
    const ushort* __restrict__ Apack, const ushort* __restrict__ Bpack,
    float* __restrict__ rowpart,     // [JS][BB][NN]
    float* __restrict__ colpart)     // [IG][BB][MM]
{
    __shared__ unsigned ldsCol[1024];

    const int js = blockIdx.x, ig = blockIdx.y, b = blockIdx.z;
    const int tid = threadIdx.x;
    const int w = tid >> 6, lane = tid & 63;

    for (int k = tid; k < 1024; k += 256) ldsCol[k] = INFBITS;
    __syncthreads();

    const int ti0 = ig * 8 + w;                       // tile idx within batch
    const ushort* Ab = Apack + (((size_t)(b * 256 + ti0)) << 9) + lane * 8;
    short8 a0 = *(const short8*)Ab;
    short8 a1 = *(const short8*)(Ab + (4 << 9));      // +64 rows = +4 tiles

    const ushort* Bb = Bpack + (((size_t)(b * 1024 + js * 64)) << 9) + lane * 8;

    const float INF = __uint_as_float(INFBITS);
    float racc0[4] = {INF, INF, INF, INF};
    float racc1[4] = {INF, INF, INF, INF};

    for (int jt = 0; jt < 64; ++jt) {
        short8 bf = *(const short8*)(Bb + ((size_t)jt << 9));
        f32x4 zero = {0.f, 0.f, 0.f, 0.f};
        f32x4 c0 = __builtin_amdgcn_mfma_f32_16x16x32_bf16(a0, bf, zero, 0, 0, 0);
        f32x4 c1 = __builtin_amdgcn_mfma_f32_16x16x32_bf16(a1, bf, zero, 0, 0, 0);
#pragma unroll
        for (int r = 0; r < 4; ++r) {
            racc0[r] = fminf(racc0[r], c0[r]);
            racc1[r] = fminf(racc1[r], c1[r]);
        }
        float m0 = fminf(fminf(c0[0], c0[1]), fminf(c0[2], c0[3]));
        float m1 = fminf(fminf(c1[0], c1[1]), fminf(c1[2], c1[3]));
        float m  = fminf(m0, m1);                     // min over this wave's 32 rows
        m = fminf(m, __shfl_xor(m, 16, 64));          // min over row-groups
        m = fminf(m, __shfl_xor(m, 32, 64));
        if (lane < 16)
            atomicMin(&ldsCol[jt * 16 + lane], __float_as_uint(fmaxf(m, 0.f)));
    }

    // row mins: reduce across the 16 cols (lane&15), plain stores
#pragma unroll
    for (int mask = 1; mask < 16; mask <<= 1) {
#pragma unroll
        for (int r = 0; r < 4; ++r) {
            racc0[r] = fminf(racc0[r], __shfl_xor(racc0[r], mask, 64));
            racc1[r] = fminf(racc1[r], __shfl_xor(racc1[r], mask, 64));
        }
    }
    if ((lane & 15) == 0) {
        const int rg = lane >> 4;
        float* rp = rowpart + (((size_t)js * BB + b) << 12);
        const int i0 = ig * 128 + w * 16 + rg * 4;
#pragma unroll
        for (int r = 0; r < 4; ++r) {
            rp[i0 + r]      = fmaxf(racc0[r], 0.f);
            rp[i0 + 64 + r] = fmaxf(racc1[r], 0.f);
        }
    }

    __syncthreads();
    float* cp = colpart + (((size_t)ig * BB + b) << 14) + js * 1024;
    for (int k = tid; k < 1024; k += 256)
        cp[k] = __uint_as_float(ldsCol[k]);
}

// ---------- reduce1: 128 blocks, min over partials + sqrt + partial sums ----------
__global__ __launch_bounds__(256) void reduce1_kernel(
    const float* __restrict__ rowpart,
    const float* __restrict__ colpart,
    float* __restrict__ part)            // [128][3]
{
    const int k = blockIdx.x, b = k >> 6, s = k & 63;
    const int tid = threadIdx.x;
    const float INF = __uint_as_float(INFBITS);

    const int col = s * 256 + tid;
    float v = INF;
#pragma unroll 4
    for (int ig = 0; ig < IG; ++ig)
        v = fminf(v, colpart[(((size_t)ig * BB + b) << 14) + col]);
    float sB = sqrtf(v);

    const int row = s * 64 + (tid & 63);
    const int jq  = tid >> 6;
    float wv2 = INF;
#pragma unroll
    for (int q = 0; q < 4; ++q)
        wv2 = fminf(wv2, rowpart[(((size_t)(jq * 4 + q) * BB + b) << 12) + row]);
    __shared__ float rred[4][64];
    rred[jq][tid & 63] = wv2;
    __syncthreads();
    float sF = 0.f, mF = 0.f;
    if (tid < 64) {
        float rmn = fminf(fminf(rred[0][tid], rred[1][tid]),
                          fminf(rred[2][tid], rred[3][tid]));
        float d = sqrtf(rmn);
        sF = d; mF = d;
    }

    for (int m = 1; m < 64; m <<= 1) {
        sB += __shfl_xor(sB, m, 64);
        sF += __shfl_xor(sF, m, 64);
        mF = fmaxf(mF, __shfl_xor(mF, m, 64));
    }
    __shared__ float red[3][4];
    const int lane = tid & 63, wvi = tid >> 6;
    if (lane == 0) { red[0][wvi] = sB; red[1][wvi] = sF; red[2][wvi] = mF; }
    __syncthreads();
    if (tid == 0) {
        part[k * 3 + 0] = red[0][0] + red[0][1] + red[0][2] + red[0][3];
        part[k * 3 + 1] = red[1][0] + red[1][1] + red[1][2] + red[1][3];
        part[k * 3 + 2] = fmaxf(fmaxf(red[2][0], red[2][1]),
                                fmaxf(red[2][2], red[2][3]));
    }
}

__global__ void reduce2_kernel(const float* __restrict__ part,
                               float* __restrict__ out)
{
    const int tid = threadIdx.x;         // 128 threads: wave0 = b0, wave1 = b1
    float sB = part[tid * 3 + 0];
    float sF = part[tid * 3 + 1];
    float mF = part[tid * 3 + 2];
    for (int m = 1; m < 64; m <<= 1) {
        sB += __shfl_xor(sB, m, 64);
        sF += __shfl_xor(sF, m, 64);
        mF = fmaxf(mF, __shfl_xor(mF, m, 64));
    }
    __shared__ float red[2][3];
    if ((tid & 63) == 0) { red[tid >> 6][0] = sB; red[tid >> 6][1] = sF; red[tid >> 6][2] = mF; }
    __syncthreads();
    if (tid == 0) {
        float l0 = 5.f * red[0][0] / (float)MM + red[0][1] / (float)NN + red[0][2];
        float l1 = 5.f * red[1][0] / (float)MM + red[1][1] / (float)NN + red[1][2];
        *out = 0.5f * (l0 + l1);
    }
}

extern "C" void kernel_launch(void* const* d_in, const int* in_sizes, int n_in,
                              void* d_out, int out_size, void* d_ws, size_t ws_size,
                              hipStream_t stream) {
    const float* sampled = (const float*)d_in[0];
    const float* raw     = (const float*)d_in[1];

    ushort* Apack  = (ushort*)d_ws;                          // 2*256 tiles * 1KB = 512 KB
    ushort* Bpack  = Apack + (size_t)BB * 256 * 512;         // 2*1024 tiles * 1KB = 2 MB
    float* colpart = (float*)(Bpack + (size_t)BB * 1024 * 512);  // IG*BB*MM = 4 MB
    float* rowpart = colpart + (size_t)IG * BB * MM;         // JS*BB*NN = 512 KB
    float* part    = rowpart + (size_t)JS * BB * NN;
    float* out     = (float*)d_out;

    pack_kernel<<<(BB * (NN + MM)) / 256, 256, 0, stream>>>(sampled, raw, Apack, Bpack);
    pair_kernel<<<dim3(JS, IG, BB), 256, 0, stream>>>(Apack, Bpack, rowpart, colpart);
    reduce1_kernel<<<128, 256, 0, stream>>>(rowpart, colpart, part);
    reduce2_kernel<<<1, 128, 0, stream>>>(part, out);
}

// Round 12
// 37.293 us; speedup vs baseline: 8.5159x; 1.3058x over previous
//
#include <hip/hip_runtime.h>
#include <math.h>

constexpr int BB = 2, NN = 4096, MM = 16384;
constexpr int JS = 32;                   // col strips (512 cols each)
constexpr int IG = 16;                   // row groups (256 rows each)
constexpr int SC = 512;                  // cols per strip
constexpr int ST = SC / 16;              // 32 B-tiles per strip
constexpr unsigned INFBITS = 0x7F800000u;
constexpr ushort ONEB = 0x3F80;          // bf16 1.0

typedef __attribute__((ext_vector_type(8))) short  short8;
typedef __attribute__((ext_vector_type(8))) ushort ushort8;
typedef __attribute__((ext_vector_type(4))) float  f32x4;

// sq = |s|^2 + |r|^2 - 2 s.r folded into one mfma_16x16x32_bf16 K-vector
// (hi/lo split; verified absmax 0.0 in R11):
//  A k0-5: hi(-2s)xyz twice, k6-8: lo(-2s), k9-10: hi/lo(|s|^2), k11-12: 1
//  B k0-2: hi(r), k3-5: lo(r), k6-8: hi(r), k9-10: 1, k11-12: hi/lo(|r|^2)
// Fragment layout (R11-verified): lane l = point (l&15), K-chunk (l>>4).
__device__ __forceinline__ ushort f2bf(float f) {
    unsigned u = __float_as_uint(f);
    u += 0x7FFF + ((u >> 16) & 1);
    return (ushort)(u >> 16);
}
__device__ __forceinline__ void split2(float v, ushort& h, ushort& l) {
    h = f2bf(v);
    l = f2bf(v - __uint_as_float(((unsigned)h) << 16));
}

__global__ __launch_bounds__(256, 4) void pair_kernel(
    const float* __restrict__ sampled,   // [BB][NN][4]
    const float* __restrict__ raw,       // [BB][MM][4]
    float* __restrict__ rowpart,         // [JS][BB][NN]
    float* __restrict__ colpart)         // [IG][BB][MM]
{
    __shared__ ushort ldsB[ST * 512];    // 32 KB: tile jt at jt*512, frag-linear
    __shared__ float  ldsCol[4][SC];     // 8 KB per-wave col mins

    const int js = blockIdx.x, ig = blockIdx.y, b = blockIdx.z;
    const int tid = threadIdx.x, w = tid >> 6, lane = tid & 63;
    const int p = lane & 15, c = lane >> 4;
    const int j0 = js * SC, i0 = ig * 256;

    // ---- pack this strip's 512 raw points into LDS B-fragments ----
    const float4* rp4 = (const float4*)raw + (size_t)b * MM + j0;
    for (int t = tid; t < SC; t += 256) {
        float4 v = rp4[t];
        float n = fmaf(v.z, v.z, fmaf(v.y, v.y, v.x * v.x));
        ushort hx,lx,hy,ly,hz,lz,hn,ln;
        split2(v.x, hx, lx); split2(v.y, hy, ly);
        split2(v.z, hz, lz); split2(n, hn, ln);
        ushort* dst = ldsB + (t >> 4) * 512 + (t & 15) * 8;
        ushort8 zz = ushort8{0,0,0,0,0,0,0,0};
        *(ushort8*)(dst)       = ushort8{hx,hy,hz,lx,ly,lz,hx,hy};
        *(ushort8*)(dst + 128) = ushort8{hz,ONEB,ONEB,hn,ln,0,0,0};
        *(ushort8*)(dst + 256) = zz;
        *(ushort8*)(dst + 384) = zz;
    }

    // ---- build this wave's 4 A-fragments in registers (rows i0+w*64..+63) ----
    short8 afr[4];
    const float4* sp4 = (const float4*)sampled + (size_t)b * NN + i0 + w * 64 + p;
#pragma unroll
    for (int f = 0; f < 4; ++f) {
        float4 v = sp4[f * 16];
        float n = fmaf(v.z, v.z, fmaf(v.y, v.y, v.x * v.x));
        ushort hx,lx,hy,ly,hz,lz,hn,ln;
        split2(-2.f * v.x, hx, lx); split2(-2.f * v.y, hy, ly);
        split2(-2.f * v.z, hz, lz); split2(n, hn, ln);
        ushort8 w0 = ushort8{hx,hy,hz,hx,hy,hz,lx,ly};
        ushort8 w1 = ushort8{lz,hn,ln,ONEB,ONEB,0,0,0};
        ushort8 zz = ushort8{0,0,0,0,0,0,0,0};
        ushort8 sel = (c == 0) ? w0 : ((c == 1) ? w1 : zz);
        afr[f] = *(short8*)&sel;
    }
    __syncthreads();

    const float INF = __uint_as_float(INFBITS);
    float racc[4][4];
#pragma unroll
    for (int f = 0; f < 4; ++f)
#pragma unroll
        for (int r = 0; r < 4; ++r) racc[f][r] = INF;

    const f32x4 zero = {0.f, 0.f, 0.f, 0.f};

    for (int jt = 0; jt < ST; ++jt) {
        short8 bf = *(const short8*)(ldsB + jt * 512 + lane * 8);
        f32x4 c0 = __builtin_amdgcn_mfma_f32_16x16x32_bf16(afr[0], bf, zero, 0, 0, 0);
        f32x4 c1 = __builtin_amdgcn_mfma_f32_16x16x32_bf16(afr[1], bf, zero, 0, 0, 0);
        f32x4 c2 = __builtin_amdgcn_mfma_f32_16x16x32_bf16(afr[2], bf, zero, 0, 0, 0);
        f32x4 c3 = __builtin_amdgcn_mfma_f32_16x16x32_bf16(afr[3], bf, zero, 0, 0, 0);
#pragma unroll
        for (int r = 0; r < 4; ++r) {
            racc[0][r] = fminf(racc[0][r], c0[r]);
            racc[1][r] = fminf(racc[1][r], c1[r]);
            racc[2][r] = fminf(racc[2][r], c2[r]);
            racc[3][r] = fminf(racc[3][r], c3[r]);
        }
        float m0 = fminf(fminf(c0[0], c0[1]), fminf(c0[2], c0[3]));
        float m1 = fminf(fminf(c1[0], c1[1]), fminf(c1[2], c1[3]));
        float m2 = fminf(fminf(c2[0], c2[1]), fminf(c2[2], c2[3]));
        float m3 = fminf(fminf(c3[0], c3[1]), fminf(c3[2], c3[3]));
        float m  = fminf(fminf(m0, m1), fminf(m2, m3));   // min over wave's 64 rows (this 16-col tile)
        m = fminf(m, __shfl_xor(m, 16, 64));
        m = fminf(m, __shfl_xor(m, 32, 64));
        if (lane < 16) ldsCol[w][jt * 16 + lane] = m;     // each slot written once
    }

    // ---- row mins: reduce across the 16 cols (lane&15), plain stores ----
#pragma unroll
    for (int mask = 1; mask < 16; mask <<= 1)
#pragma unroll
        for (int f = 0; f < 4; ++f)
#pragma unroll
            for (int r = 0; r < 4; ++r)
                racc[f][r] = fminf(racc[f][r], __shfl_xor(racc[f][r], mask, 64));
    if (p == 0) {                                          // lanes 0,16,32,48
        float* rp = rowpart + ((size_t)js * BB + b) * NN + i0 + w * 64;
#pragma unroll
        for (int f = 0; f < 4; ++f)
#pragma unroll
            for (int r = 0; r < 4; ++r)
                rp[f * 16 + c * 4 + r] = fmaxf(racc[f][r], 0.f);
    }

    // ---- col mins: combine 4 waves, plain store ----
    __syncthreads();
    float* cp = colpart + ((size_t)ig * BB + b) * MM + j0;
    for (int t = tid; t < SC; t += 256) {
        float v = fminf(fminf(ldsCol[0][t], ldsCol[1][t]),
                        fminf(ldsCol[2][t], ldsCol[3][t]));
        cp[t] = fmaxf(v, 0.f);
    }
}

// ---------- reduce1: 128 blocks, min over partials + sqrt + partial sums ----------
__global__ __launch_bounds__(256) void reduce1_kernel(
    const float* __restrict__ rowpart,
    const float* __restrict__ colpart,
    float* __restrict__ part)            // [128][3]
{
    const int k = blockIdx.x, b = k >> 6, s = k & 63;
    const int tid = threadIdx.x;
    const float INF = __uint_as_float(INFBITS);

    const int col = s * 256 + tid;
    float v = INF;
#pragma unroll 4
    for (int ig = 0; ig < IG; ++ig)
        v = fminf(v, colpart[((size_t)ig * BB + b) * MM + col]);
    float sB = sqrtf(v);

    const int row = s * 64 + (tid & 63);
    const int jq  = tid >> 6;
    float wv2 = INF;
#pragma unroll
    for (int q = 0; q < JS / 4; ++q)
        wv2 = fminf(wv2, rowpart[((size_t)(jq * (JS / 4) + q) * BB + b) * NN + row]);
    __shared__ float rred[4][64];
    rred[jq][tid & 63] = wv2;
    __syncthreads();
    float sF = 0.f, mF = 0.f;
    if (tid < 64) {
        float rmn = fminf(fminf(rred[0][tid], rred[1][tid]),
                          fminf(rred[2][tid], rred[3][tid]));
        float d = sqrtf(rmn);
        sF = d; mF = d;
    }

    for (int m = 1; m < 64; m <<= 1) {
        sB += __shfl_xor(sB, m, 64);
        sF += __shfl_xor(sF, m, 64);
        mF = fmaxf(mF, __shfl_xor(mF, m, 64));
    }
    __shared__ float red[3][4];
    const int lane = tid & 63, wvi = tid >> 6;
    if (lane == 0) { red[0][wvi] = sB; red[1][wvi] = sF; red[2][wvi] = mF; }
    __syncthreads();
    if (tid == 0) {
        part[k * 3 + 0] = red[0][0] + red[0][1] + red[0][2] + red[0][3];
        part[k * 3 + 1] = red[1][0] + red[1][1] + red[1][2] + red[1][3];
        part[k * 3 + 2] = fmaxf(fmaxf(red[2][0], red[2][1]),
                                fmaxf(red[2][2], red[2][3]));
    }
}

__global__ void reduce2_kernel(const float* __restrict__ part,
                               float* __restrict__ out)
{
    const int tid = threadIdx.x;         // 128 threads: wave0 = b0, wave1 = b1
    float sB = part[tid * 3 + 0];
    float sF = part[tid * 3 + 1];
    float mF = part[tid * 3 + 2];
    for (int m = 1; m < 64; m <<= 1) {
        sB += __shfl_xor(sB, m, 64);
        sF += __shfl_xor(sF, m, 64);
        mF = fmaxf(mF, __shfl_xor(mF, m, 64));
    }
    __shared__ float red[2][3];
    if ((tid & 63) == 0) { red[tid >> 6][0] = sB; red[tid >> 6][1] = sF; red[tid >> 6][2] = mF; }
    __syncthreads();
    if (tid == 0) {
        float l0 = 5.f * red[0][0] / (float)MM + red[0][1] / (float)NN + red[0][2];
        float l1 = 5.f * red[1][0] / (float)MM + red[1][1] / (float)NN + red[1][2];
        *out = 0.5f * (l0 + l1);
    }
}

extern "C" void kernel_launch(void* const* d_in, const int* in_sizes, int n_in,
                              void* d_out, int out_size, void* d_ws, size_t ws_size,
                              hipStream_t stream) {
    const float* sampled = (const float*)d_in[0];
    const float* raw     = (const float*)d_in[1];
    float* rowpart = (float*)d_ws;                          // JS*BB*NN = 1 MB
    float* colpart = rowpart + (size_t)JS * BB * NN;        // IG*BB*MM = 2 MB
    float* part    = colpart + (size_t)IG * BB * MM;        // 384 floats
    float* out     = (float*)d_out;

    pair_kernel<<<dim3(JS, IG, BB), 256, 0, stream>>>(sampled, raw, rowpart, colpart);
    reduce1_kernel<<<128, 256, 0, stream>>>(rowpart, colpart, part);
    reduce2_kernel<<<1, 128, 0, stream>>>(part, out);
}